// Round 1
// 328.614 us; speedup vs baseline: 1.0326x; 1.0326x over previous
//
#include <hip/hip_runtime.h>
#include <hip/hip_bf16.h>

// Problem: B=32, L=1024, F=1024, H=1024, D=1024 — inputs fp32, OUTPUT fp32.
//   h1 = feat@W1 + b1; h2 = hidden@W2 + b2; att = tanh(h1 + h2[:,None,:])
//   score = att@Wp; w = softmax_L(score); out[b][f] = sum_l w[b][l]*feat[b][l][f]
//
// R9: single full-batch 256^2-tile 8-phase GEMM (counted vmcnt(6), dbuf LDS,
//     setprio, 2-way-free XOR swizzle). Halves merged: 1 prep + 1 gemm.
//     score partials 8 -> 4 (softmax takes np). Fill (77us, harness) untouchable.

typedef __attribute__((ext_vector_type(8))) __bf16 bf16x8;
typedef __attribute__((ext_vector_type(4))) float f32x4;

#define BM 128
#define BN 128
#define LDK 40  // fallback path LDS k-stride
#define NT 16   // K tiles of 64 in primary gemm

static __device__ __forceinline__ ushort f2bf(float x) {  // RNE fp32->bf16
  unsigned u = __float_as_uint(x);
  return (ushort)((u + 0x7fffu + ((u >> 16) & 1u)) >> 16);
}

typedef __attribute__((address_space(1))) void gbl_t;
typedef __attribute__((address_space(3))) void lds_t;
static __device__ __forceinline__ void gl_lds16(const void* g, void* l) {
  __builtin_amdgcn_global_load_lds((gbl_t*)g, (lds_t*)l, 16, 0, 0);
}

static __device__ __forceinline__ bf16x8 cvt8(float4 lo, float4 hi) {
  __hip_bfloat162 c0 = __float22bfloat162_rn({lo.x, lo.y});
  __hip_bfloat162 c1 = __float22bfloat162_rn({lo.z, lo.w});
  __hip_bfloat162 c2 = __float22bfloat162_rn({hi.x, hi.y});
  __hip_bfloat162 c3 = __float22bfloat162_rn({hi.z, hi.w});
  union { int4 i; bf16x8 v; } u;
  u.i.x = *(int*)&c0; u.i.y = *(int*)&c1; u.i.z = *(int*)&c2; u.i.w = *(int*)&c3;
  return u.v;
}

// fast tanh: 1 - 2/(e^{2x}+1). exp(+inf)->inf gives 1; exp(-inf)->0 gives -1.
static __device__ __forceinline__ float tanh_fast(float x) {
  float e = __expf(2.f * x);
  return 1.f - 2.f / (e + 1.f);
}

// ---------- prep: [0,cvt_blocks) feat cvt | +256 W1 transpose | +1024 h2 ----------
__global__ __launch_bounds__(256) void prep_kernel(
    const float* __restrict__ feat_half, ushort* __restrict__ featb,
    const float* __restrict__ W1, ushort* __restrict__ w1t,
    const float* __restrict__ hidden, const float* __restrict__ W2,
    const float* __restrict__ b2, float* __restrict__ h2p, int cvt_blocks) {
  __shared__ float smem[64 * 65];
  const int bx = blockIdx.x, tid = threadIdx.x;
  if (bx < cvt_blocks) {
    // feat fp32 -> bf16, 8 elems/thread
    const size_t i8 = ((size_t)bx * 256 + tid) * 8;
    float4 a = *(const float4*)(feat_half + i8);
    float4 c = *(const float4*)(feat_half + i8 + 4);
    union { bf16x8 v; int4 i; } u;
    u.v = cvt8(a, c);
    *(int4*)(featb + i8) = u.i;
  } else if (bx < cvt_blocks + 256) {
    // W1 [F][D] fp32 -> W1T [D][F] bf16, 64x64 tiles
    const int t = bx - cvt_blocks;
    const int tc = t & 15, tr = t >> 4;
    float (*tt)[65] = (float(*)[65])smem;
    const int r = tid >> 4, c4 = (tid & 15) * 4;
#pragma unroll
    for (int p = 0; p < 4; ++p) {
      const int rr = p * 16 + r;
      float4 v = *(const float4*)(W1 + (size_t)(tr * 64 + rr) * 1024 + tc * 64 + c4);
      tt[rr][c4] = v.x; tt[rr][c4 + 1] = v.y; tt[rr][c4 + 2] = v.z; tt[rr][c4 + 3] = v.w;
    }
    __syncthreads();
    const int cc = tid >> 3, r8 = (tid & 7) * 8;
#pragma unroll
    for (int p = 0; p < 2; ++p) {
      const int c = p * 32 + cc;
      ushort tmp[8];
#pragma unroll
      for (int j = 0; j < 8; ++j) tmp[j] = f2bf(tt[r8 + j][c]);
      *(int4*)(w1t + (size_t)(tc * 64 + c) * 1024 + tr * 64 + r8) = *(int4*)tmp;
    }
  } else {
    // h2p[z][b][d] = hidden[b][128z:+128] @ W2[...,d] (+b2 at z==0)
    const int t = bx - cvt_blocks - 256;  // 0..1023
    const int dblk = t & 3, b = (t >> 2) & 31, z = t >> 7;
    const int d = dblk * 256 + tid;
    const int k0 = z * 128;
    float* h = smem;
    if (tid < 128) h[tid] = hidden[b * 1024 + k0 + tid];
    __syncthreads();
    float acc = (z == 0) ? b2[d] : 0.f;
#pragma unroll 8
    for (int k = 0; k < 128; ++k)
      acc += h[k] * W2[(size_t)(k0 + k) * 1024 + d];
    h2p[z * 32768 + b * 1024 + d] = acc;
  }
}

// ======== PRIMARY: 256^2-tile 8-phase bf16 GEMM, BK=64, 512 thr / 8 waves ========
// LDS per operand per dbuf: 2 k-halves x [256][32] bf16 (16KB halves, DMA-linear).
// Swizzle: LDS chunk c holds global chunk c ^ ((row>>1)&3)  (2-way = free).
// Half order per tile: H0=Bk0, H1=Ak0, H2=Bk1, H3=Ak1.
// Phase p of tile t reads only kslice (p>=3), so half X of buf[cur] is dead after
// its last read-phase's 2nd barrier -> staging t+2 into cur at phases 2..4 is safe.
// vmcnt(6) once per tile (phases 4/8 of the 2-tile iteration) = 3 half-tiles in
// flight; tail: vmcnt(0) at t=NT-2.

#define PH_BAR1() { asm volatile("" ::: "memory"); __builtin_amdgcn_s_barrier(); }
#define PH_BAR2() { __builtin_amdgcn_sched_barrier(0); asm volatile("" ::: "memory"); __builtin_amdgcn_s_barrier(); }

#define STAGE_A(TILE, KH, BUF) {                                               \
    const int ko_ = (TILE) * 64 + (KH) * 32;                                   \
    gl_lds16(featb + a_off[0] + ko_, (char*)&ldsA[BUF][KH][0][0] + l_off0);    \
    gl_lds16(featb + a_off[1] + ko_, (char*)&ldsA[BUF][KH][0][0] + l_off1); }
#define STAGE_B(TILE, KH, BUF) {                                               \
    const int ko_ = (TILE) * 64 + (KH) * 32;                                   \
    gl_lds16(w1t + b_off[0] + ko_, (char*)&ldsB[BUF][KH][0][0] + l_off0);      \
    gl_lds16(w1t + b_off[1] + ko_, (char*)&ldsB[BUF][KH][0][0] + l_off1); }

#define LDA_F(I, S, BUF, DST) {                                                \
    const int r_ = wm * 128 + (I) * 16 + lrow;                                 \
    DST = *(const bf16x8*)&ldsA[BUF][S][r_][(quad ^ ((r_ >> 1) & 3)) * 8]; }
#define LDB_F(J, S, BUF, DST) {                                                \
    const int r_ = wn * 64 + (J) * 16 + lrow;                                  \
    DST = *(const bf16x8*)&ldsB[BUF][S][r_][(quad ^ ((r_ >> 1) & 3)) * 8]; }

#define MFMA4(IB, AF)                                                          \
  acc[IB][0] = __builtin_amdgcn_mfma_f32_16x16x32_bf16(AF, bf0, acc[IB][0], 0, 0, 0); \
  acc[IB][1] = __builtin_amdgcn_mfma_f32_16x16x32_bf16(AF, bf1, acc[IB][1], 0, 0, 0); \
  acc[IB][2] = __builtin_amdgcn_mfma_f32_16x16x32_bf16(AF, bf2, acc[IB][2], 0, 0, 0); \
  acc[IB][3] = __builtin_amdgcn_mfma_f32_16x16x32_bf16(AF, bf3, acc[IB][3], 0, 0, 0);

__global__ __launch_bounds__(512, 2) void gemm_score_8ph_kernel(
    const ushort* __restrict__ featb,  // bf16 [32768][1024]
    const ushort* __restrict__ w1t,    // bf16 [1024][1024]
    const float* __restrict__ b1, const float* __restrict__ h2p,
    const float* __restrict__ wp, float* __restrict__ score_p) {
  __shared__ ushort ldsA[2][2][256][32];  // [buf][khalf][row][k] 64KB
  __shared__ ushort ldsB[2][2][256][32];  // 64KB
  __shared__ float hbl[256], wpl[256];
  __shared__ float sred[2][3][128];

  const int tid = threadIdx.x;
  const int row0 = blockIdx.x * 256;
  const int col0 = blockIdx.y * 256;
  const int b = row0 >> 10;
  const int wave = tid >> 6, lane = tid & 63;
  const int wm = wave >> 2, wn = wave & 3;  // 2M x 4N
  const int lrow = lane & 15, quad = lane >> 4;

  // preloop: hb (b1 + sum of h2 partials) and wp slices for this col block
  if (tid < 256) {
    const int d = col0 + tid;
    float hv = b1[d];
#pragma unroll
    for (int p = 0; p < 8; ++p) hv += h2p[p * 32768 + b * 1024 + d];
    hbl[tid] = hv;
  } else {
    wpl[tid - 256] = wp[col0 + tid - 256];
  }

  // staging offsets: slot s covers (row r=s>>2, lds-chunk c=s&3) of a 16KB half;
  // source global chunk q = c ^ ((r>>1)&3)  (pre-swizzled source, linear dest)
  int a_off[2], b_off[2];
  int l_off0, l_off1;
  {
    const int s0 = wave * 128 + lane;
    const int r0 = s0 >> 2, c0 = s0 & 3;
    const int q0 = c0 ^ ((r0 >> 1) & 3);
    a_off[0] = (row0 + r0) * 1024 + q0 * 8;
    b_off[0] = (col0 + r0) * 1024 + q0 * 8;
    const int s1 = s0 + 64;
    const int r1 = s1 >> 2, c1 = s1 & 3;
    const int q1 = c1 ^ ((r1 >> 1) & 3);
    a_off[1] = (row0 + r1) * 1024 + q1 * 8;
    b_off[1] = (col0 + r1) * 1024 + q1 * 8;
    l_off0 = (wave * 128) * 16;       // wave-uniform LDS byte base, lane*16 added by HW
    l_off1 = (wave * 128 + 64) * 16;
  }

  f32x4 acc[8][4] = {};

  // prologue: tile0 fully (H0..H3), then tile1 H0..H2
  STAGE_B(0, 0, 0); STAGE_A(0, 0, 0); STAGE_B(0, 1, 0); STAGE_A(0, 1, 0);
  asm volatile("s_waitcnt vmcnt(4)" ::: "memory");
  STAGE_B(1, 0, 1); STAGE_A(1, 0, 1); STAGE_B(1, 1, 1);
  asm volatile("s_waitcnt vmcnt(6) lgkmcnt(0)" ::: "memory");
  __builtin_amdgcn_s_barrier();

#pragma unroll 2
  for (int t = 0; t < NT; ++t) {
    const int cur = t & 1, nxt = cur ^ 1;
    bf16x8 af0, af1, af2, af3, bf0, bf1, bf2, bf3;

    // ---- phase 1: kslice0, rows i0-3; stage (t+1).H3 = A k1 -> nxt ----
    LDB_F(0, 0, cur, bf0); LDB_F(1, 0, cur, bf1);
    LDB_F(2, 0, cur, bf2); LDB_F(3, 0, cur, bf3);
    LDA_F(0, 0, cur, af0); LDA_F(1, 0, cur, af1);
    LDA_F(2, 0, cur, af2); LDA_F(3, 0, cur, af3);
    if (t + 1 < NT) STAGE_A(t + 1, 1, nxt);
    PH_BAR1();
    __builtin_amdgcn_s_setprio(1);
    MFMA4(0, af0); MFMA4(1, af1); MFMA4(2, af2); MFMA4(3, af3);
    __builtin_amdgcn_s_setprio(0);
    PH_BAR2();

    // ---- phase 2: kslice0, rows i4-7; stage (t+2).H0 = B k0 -> cur ----
    LDA_F(4, 0, cur, af0); LDA_F(5, 0, cur, af1);
    LDA_F(6, 0, cur, af2); LDA_F(7, 0, cur, af3);
    if (t + 2 < NT) STAGE_B(t + 2, 0, cur);
    PH_BAR1();
    __builtin_amdgcn_s_setprio(1);
    MFMA4(4, af0); MFMA4(5, af1); MFMA4(6, af2); MFMA4(7, af3);
    __builtin_amdgcn_s_setprio(0);
    PH_BAR2();

    // ---- phase 3: kslice1, rows i0-3; stage (t+2).H1 = A k0 -> cur ----
    LDB_F(0, 1, cur, bf0); LDB_F(1, 1, cur, bf1);
    LDB_F(2, 1, cur, bf2); LDB_F(3, 1, cur, bf3);
    LDA_F(0, 1, cur, af0); LDA_F(1, 1, cur, af1);
    LDA_F(2, 1, cur, af2); LDA_F(3, 1, cur, af3);
    if (t + 2 < NT) STAGE_A(t + 2, 0, cur);
    PH_BAR1();
    __builtin_amdgcn_s_setprio(1);
    MFMA4(0, af0); MFMA4(1, af1); MFMA4(2, af2); MFMA4(3, af3);
    __builtin_amdgcn_s_setprio(0);
    PH_BAR2();

    // ---- phase 4: kslice1, rows i4-7; stage (t+2).H2 = B k1 -> cur ----
    LDA_F(4, 1, cur, af0); LDA_F(5, 1, cur, af1);
    LDA_F(6, 1, cur, af2); LDA_F(7, 1, cur, af3);
    if (t + 2 < NT) STAGE_B(t + 2, 1, cur);
    if (t < NT - 2) {
      asm volatile("s_waitcnt vmcnt(6)" ::: "memory");  // tile t+1 fully landed
    } else {
      asm volatile("s_waitcnt vmcnt(0)" ::: "memory");  // tail drain
    }
    PH_BAR1();
    __builtin_amdgcn_s_setprio(1);
    MFMA4(4, af0); MFMA4(5, af1); MFMA4(6, af2); MFMA4(7, af3);
    __builtin_amdgcn_s_setprio(0);
    PH_BAR2();
  }

  // ---- epilogue: score partial per row over this 256-col block ----
  float hbv[4], wpv[4];
#pragma unroll
  for (int j = 0; j < 4; ++j) {
    const int idx = wn * 64 + j * 16 + lrow;
    hbv[j] = hbl[idx];
    wpv[j] = wpl[idx];
  }
  float rs[8][4];
#pragma unroll
  for (int i = 0; i < 8; ++i) {
#pragma unroll
    for (int r = 0; r < 4; ++r) {
      float s = 0.f;
#pragma unroll
      for (int j = 0; j < 4; ++j)
        s += tanh_fast(acc[i][j][r] + hbv[j]) * wpv[j];
      s += __shfl_xor(s, 8);
      s += __shfl_xor(s, 4);
      s += __shfl_xor(s, 2);
      s += __shfl_xor(s, 1);
      rs[i][r] = s;
    }
  }
  if (wn != 0 && lrow == 0) {
#pragma unroll
    for (int i = 0; i < 8; ++i)
#pragma unroll
      for (int r = 0; r < 4; ++r)
        sred[wm][wn - 1][i * 16 + quad * 4 + r] = rs[i][r];
  }
  __syncthreads();
  if (wn == 0 && lrow == 0) {
#pragma unroll
    for (int i = 0; i < 8; ++i)
#pragma unroll
      for (int r = 0; r < 4; ++r) {
        const int ro = i * 16 + quad * 4 + r;
        score_p[(size_t)blockIdx.y * 32768 + row0 + wm * 128 + ro] =
            rs[i][r] + sred[wm][0][ro] + sred[wm][1][ro] + sred[wm][2][ro];
      }
  }
}

// ======== FALLBACK (small ws): staging-cvt GEMM, fp32 feat direct ========
#define GEMM_PRELOOP()                                                         \
  if (tid < 128) {                                                             \
    const int d = col0 + tid;                                                  \
    float hv = b1[d];                                                          \
    _Pragma("unroll") for (int p = 0; p < 8; ++p)                              \
        hv += h2p[p * 32768 + b * 1024 + d];                                   \
    hbl[tid] = hv;                                                             \
  } else {                                                                     \
    wpl[tid - 128] = wp[col0 + tid - 128];                                     \
  }

#define GEMM_EPILOGUE(ROWG)                                                    \
  float hbv[4], wpv[4];                                                        \
  _Pragma("unroll") for (int j = 0; j < 4; ++j) {                              \
    const int idx = wn * 64 + j * 16 + lrow;                                   \
    hbv[j] = hbl[idx];                                                         \
    wpv[j] = wpl[idx];                                                         \
  }                                                                            \
  float rsum[4][4];                                                            \
  _Pragma("unroll") for (int i = 0; i < 4; ++i) {                              \
    _Pragma("unroll") for (int r = 0; r < 4; ++r) {                            \
      float s = 0.f;                                                           \
      _Pragma("unroll") for (int j = 0; j < 4; ++j)                            \
          s += tanh_fast(acc[i][j][r] + hbv[j]) * wpv[j];                      \
      s += __shfl_xor(s, 8);                                                   \
      s += __shfl_xor(s, 4);                                                   \
      s += __shfl_xor(s, 2);                                                   \
      s += __shfl_xor(s, 1);                                                   \
      rsum[i][r] = s;                                                          \
    }                                                                          \
  }                                                                            \
  if (wn == 1 && lrow == 0) {                                                  \
    _Pragma("unroll") for (int i = 0; i < 4; ++i)                              \
        _Pragma("unroll") for (int r = 0; r < 4; ++r)                          \
            sred[wm][i * 16 + quad * 4 + r] = rsum[i][r];                      \
  }                                                                            \
  __syncthreads();                                                             \
  if (wn == 0 && lrow == 0) {                                                  \
    _Pragma("unroll") for (int i = 0; i < 4; ++i)                              \
        _Pragma("unroll") for (int r = 0; r < 4; ++r) {                        \
          const int ro = wm * 64 + i * 16 + quad * 4 + r;                      \
          score_p[(size_t)blockIdx.y * 32768 + (ROWG) + ro] =                  \
              rsum[i][r] + sred[wm][ro & 63];                                  \
        }                                                                      \
  }

__global__ __launch_bounds__(256) void gemm_score_cvt_kernel(
    const float* __restrict__ feat, const ushort* __restrict__ w1t,
    const float* __restrict__ b1, const float* __restrict__ h2p,
    const float* __restrict__ wp, float* __restrict__ score_p) {
  __shared__ ushort ldsA[BM * LDK];
  __shared__ ushort ldsB[BN * LDK];
  __shared__ float sred[2][64];
  __shared__ float hbl[128], wpl[128];
  const int tid = threadIdx.x;
  const int row0 = blockIdx.x * BM;
  const int col0 = blockIdx.y * BN;
  const int b = row0 >> 10;

  const int wave = tid >> 6, lane = tid & 63;
  const int wm = wave & 1, wn = wave >> 1;
  const int lrow = lane & 15, quad = lane >> 4;

  GEMM_PRELOOP()

  const int arow = tid >> 1;
  const int akof = (tid & 1) * 16;
  const int brow = tid >> 2;
  const int bkof = (tid & 3) * 8;

  f32x4 acc[4][4] = {};

  for (int k0 = 0; k0 < 1024; k0 += 32) {
    {
      const float* ap = feat + (size_t)(row0 + arow) * 1024 + k0 + akof;
      float4 v0 = *(const float4*)(ap + 0);
      float4 v1 = *(const float4*)(ap + 4);
      float4 v2 = *(const float4*)(ap + 8);
      float4 v3 = *(const float4*)(ap + 12);
      union { bf16x8 v; int4 i; } w0, w1;
      w0.v = cvt8(v0, v1);
      w1.v = cvt8(v2, v3);
      *(int4*)&ldsA[arow * LDK + akof] = w0.i;
      *(int4*)&ldsA[arow * LDK + akof + 8] = w1.i;
    }
#pragma unroll
    for (int p = 0; p < 2; ++p) {
      const int m = p * 64 + brow;
      *(int4*)&ldsB[m * LDK + bkof] =
          *(const int4*)(w1t + (size_t)(col0 + m) * 1024 + k0 + bkof);
    }
    __syncthreads();
    bf16x8 af[4], bfr[4];
#pragma unroll
    for (int i = 0; i < 4; ++i)
      af[i] = *(const bf16x8*)&ldsA[(wm * 64 + i * 16 + lrow) * LDK + quad * 8];
#pragma unroll
    for (int j = 0; j < 4; ++j)
      bfr[j] = *(const bf16x8*)&ldsB[(wn * 64 + j * 16 + lrow) * LDK + quad * 8];
#pragma unroll
    for (int i = 0; i < 4; ++i)
#pragma unroll
      for (int j = 0; j < 4; ++j)
        acc[i][j] = __builtin_amdgcn_mfma_f32_16x16x32_bf16(
            af[i], bfr[j], acc[i][j], 0, 0, 0);
    __syncthreads();
  }

  GEMM_EPILOGUE(row0)
}

// -------- softmax over L per b (sums np partials); also zeroes out[b][:] --------
__global__ __launch_bounds__(256) void softmax_kernel(
    const float* __restrict__ score_p, float* __restrict__ w,
    float* __restrict__ out, int np) {
  const int b = blockIdx.x, tid = threadIdx.x;
  const int lane = tid & 63, wv = tid >> 6;
  __shared__ float sm[4], ss[4];
  float v[4];
  float mx = -1e30f;
#pragma unroll
  for (int i = 0; i < 4; ++i) {
    const int idx = b * 1024 + i * 256 + tid;
    out[idx] = 0.f;  // d_out poisoned; context atomicAdds later
    float s = 0.f;
    for (int p = 0; p < np; ++p) s += score_p[p * 32768 + idx];
    v[i] = s;
    mx = fmaxf(mx, s);
  }
#pragma unroll
  for (int off = 32; off; off >>= 1) mx = fmaxf(mx, __shfl_xor(mx, off));
  if (lane == 0) sm[wv] = mx;
  __syncthreads();
  mx = fmaxf(fmaxf(sm[0], sm[1]), fmaxf(sm[2], sm[3]));
  float sum = 0.f;
#pragma unroll
  for (int i = 0; i < 4; ++i) {
    v[i] = __expf(v[i] - mx);
    sum += v[i];
  }
#pragma unroll
  for (int off = 32; off; off >>= 1) sum += __shfl_xor(sum, off);
  if (lane == 0) ss[wv] = sum;
  __syncthreads();
  const float inv = 1.f / (ss[0] + ss[1] + ss[2] + ss[3]);
#pragma unroll
  for (int i = 0; i < 4; ++i) w[b * 1024 + i * 256 + tid] = v[i] * inv;
}

// -------- out[b][f] += sum_{l in 64-chunk} w[b][l]*feat[b][l][f] (fp32) --------
__global__ __launch_bounds__(256) void context_kernel(
    const float* __restrict__ w, const float* __restrict__ feat,
    float* __restrict__ out) {
  const int b = blockIdx.y;
  const int l0 = blockIdx.x * 64;
  const int f0 = threadIdx.x * 4;
  __shared__ float wl[64];
  if (threadIdx.x < 64) wl[threadIdx.x] = w[b * 1024 + l0 + threadIdx.x];
  __syncthreads();
  const float* fb = feat + (size_t)b * 1048576 + (size_t)l0 * 1024 + f0;
  float a0 = 0.f, a1 = 0.f, a2 = 0.f, a3 = 0.f;
#pragma unroll 8
  for (int l = 0; l < 64; ++l) {
    float4 v = *(const float4*)(fb + (size_t)l * 1024);
    const float wv = wl[l];
    a0 += wv * v.x;
    a1 += wv * v.y;
    a2 += wv * v.z;
    a3 += wv * v.w;
  }
  float* dst = out + b * 1024 + f0;
  atomicAdd(dst + 0, a0);
  atomicAdd(dst + 1, a1);
  atomicAdd(dst + 2, a2);
  atomicAdd(dst + 3, a3);
}

extern "C" void kernel_launch(void* const* d_in, const int* in_sizes, int n_in,
                              void* d_out, int out_size, void* d_ws, size_t ws_size,
                              hipStream_t stream) {
  const float* feat   = (const float*)d_in[0];
  const float* hidden = (const float*)d_in[1];
  const float* W1     = (const float*)d_in[2];
  const float* b1     = (const float*)d_in[3];
  const float* W2     = (const float*)d_in[4];
  const float* b2     = (const float*)d_in[5];
  const float* Wp     = (const float*)d_in[6];
  float* out = (float*)d_out;

  char* ws = (char*)d_ws;
  ushort* w1t    = (ushort*)ws;                  // 2 MB
  float* score_p = (float*)(ws + 2097152);       // 1 MB region ([4] or [8] x 32768)
  float* h2p     = (float*)(ws + 3145728);       // 1 MB [8][32768]
  float* wts     = (float*)(ws + 4194304);       // 128 KB
  ushort* featb  = (ushort*)(ws + 4325376);      // 64 MB (primary path only)
  const bool big_ws = ws_size >= (size_t)(4325376 + 67108864);

  if (big_ws) {
    // full-batch prep: cvt 16384 blocks + transpose 256 + h2 1024
    prep_kernel<<<17664, 256, 0, stream>>>(feat, featb, W1, w1t, hidden, W2, b2,
                                           h2p, 16384);
    gemm_score_8ph_kernel<<<dim3(128, 4), 512, 0, stream>>>(featb, w1t, b1, h2p,
                                                            Wp, score_p);
    softmax_kernel<<<32, 256, 0, stream>>>(score_p, wts, out, 4);
  } else {
    prep_kernel<<<1280, 256, 0, stream>>>(feat, featb, W1, w1t, hidden, W2, b2,
                                          h2p, 0);
    gemm_score_cvt_kernel<<<dim3(256, 8), 256, 0, stream>>>(feat, w1t, b1, h2p,
                                                            Wp, score_p);
    softmax_kernel<<<32, 256, 0, stream>>>(score_p, wts, out, 8);
  }

  context_kernel<<<dim3(16, 32), 256, 0, stream>>>(wts, feat, out);
}

// Round 2
// 325.792 us; speedup vs baseline: 1.0416x; 1.0087x over previous
//
#include <hip/hip_runtime.h>
#include <hip/hip_bf16.h>

// Problem: B=32, L=1024, F=1024, H=1024, D=1024 — inputs fp32, OUTPUT fp32.
//   h1 = feat@W1 + b1; h2 = hidden@W2 + b2; att = tanh(h1 + h2[:,None,:])
//   score = att@Wp; w = softmax_L(score); out[b][f] = sum_l w[b][l]*feat[b][l][f]
//
// R10: R9's 8-phase GEMM measured 1712 cy/phase = full load-latency exposure
//   every phase -> compiler-inserted vmcnt(0) (memory-clobber asm in barriers +
//   visible ds_reads of DMA'd LDS) defeated the counted vmcnt(6) pipeline.
//   Fix: inline-asm ds_read_b128 (LDS offsets as ints, offset:%c immediates),
//   no "memory" clobbers in loop, raw s_barrier + explicit lgkmcnt(0) +
//   sched_barrier(0) (rule 18). vmcnt(6) is the only steady-state vmem wait.

typedef __attribute__((ext_vector_type(8))) __bf16 bf16x8;
typedef __attribute__((ext_vector_type(4))) float f32x4;

#define BM 128
#define BN 128
#define LDK 40  // fallback path LDS k-stride
#define NT 16   // K tiles of 64 in primary gemm

static __device__ __forceinline__ ushort f2bf(float x) {  // RNE fp32->bf16
  unsigned u = __float_as_uint(x);
  return (ushort)((u + 0x7fffu + ((u >> 16) & 1u)) >> 16);
}

typedef __attribute__((address_space(1))) void gbl_t;
typedef __attribute__((address_space(3))) void lds_t;
static __device__ __forceinline__ void gl_lds16(const void* g, void* l) {
  __builtin_amdgcn_global_load_lds((gbl_t*)g, (lds_t*)l, 16, 0, 0);
}

typedef __attribute__((address_space(3))) const ushort lds_us_t;
static __device__ __forceinline__ unsigned lds32(const void* p) {
  return (unsigned)(size_t)(lds_us_t*)p;  // AS3 ptr = 32-bit LDS byte offset
}

static __device__ __forceinline__ bf16x8 cvt8(float4 lo, float4 hi) {
  __hip_bfloat162 c0 = __float22bfloat162_rn({lo.x, lo.y});
  __hip_bfloat162 c1 = __float22bfloat162_rn({lo.z, lo.w});
  __hip_bfloat162 c2 = __float22bfloat162_rn({hi.x, hi.y});
  __hip_bfloat162 c3 = __float22bfloat162_rn({hi.z, hi.w});
  union { int4 i; bf16x8 v; } u;
  u.i.x = *(int*)&c0; u.i.y = *(int*)&c1; u.i.z = *(int*)&c2; u.i.w = *(int*)&c3;
  return u.v;
}

// fast tanh: 1 - 2/(e^{2x}+1). exp(+inf)->inf gives 1; exp(-inf)->0 gives -1.
static __device__ __forceinline__ float tanh_fast(float x) {
  float e = __expf(2.f * x);
  return 1.f - 2.f / (e + 1.f);
}

// ---------- prep: [0,cvt_blocks) feat cvt | +256 W1 transpose | +1024 h2 ----------
__global__ __launch_bounds__(256) void prep_kernel(
    const float* __restrict__ feat_half, ushort* __restrict__ featb,
    const float* __restrict__ W1, ushort* __restrict__ w1t,
    const float* __restrict__ hidden, const float* __restrict__ W2,
    const float* __restrict__ b2, float* __restrict__ h2p, int cvt_blocks) {
  __shared__ float smem[64 * 65];
  const int bx = blockIdx.x, tid = threadIdx.x;
  if (bx < cvt_blocks) {
    // feat fp32 -> bf16, 8 elems/thread
    const size_t i8 = ((size_t)bx * 256 + tid) * 8;
    float4 a = *(const float4*)(feat_half + i8);
    float4 c = *(const float4*)(feat_half + i8 + 4);
    union { bf16x8 v; int4 i; } u;
    u.v = cvt8(a, c);
    *(int4*)(featb + i8) = u.i;
  } else if (bx < cvt_blocks + 256) {
    // W1 [F][D] fp32 -> W1T [D][F] bf16, 64x64 tiles
    const int t = bx - cvt_blocks;
    const int tc = t & 15, tr = t >> 4;
    float (*tt)[65] = (float(*)[65])smem;
    const int r = tid >> 4, c4 = (tid & 15) * 4;
#pragma unroll
    for (int p = 0; p < 4; ++p) {
      const int rr = p * 16 + r;
      float4 v = *(const float4*)(W1 + (size_t)(tr * 64 + rr) * 1024 + tc * 64 + c4);
      tt[rr][c4] = v.x; tt[rr][c4 + 1] = v.y; tt[rr][c4 + 2] = v.z; tt[rr][c4 + 3] = v.w;
    }
    __syncthreads();
    const int cc = tid >> 3, r8 = (tid & 7) * 8;
#pragma unroll
    for (int p = 0; p < 2; ++p) {
      const int c = p * 32 + cc;
      ushort tmp[8];
#pragma unroll
      for (int j = 0; j < 8; ++j) tmp[j] = f2bf(tt[r8 + j][c]);
      *(int4*)(w1t + (size_t)(tc * 64 + c) * 1024 + tr * 64 + r8) = *(int4*)tmp;
    }
  } else {
    // h2p[z][b][d] = hidden[b][128z:+128] @ W2[...,d] (+b2 at z==0)
    const int t = bx - cvt_blocks - 256;  // 0..1023
    const int dblk = t & 3, b = (t >> 2) & 31, z = t >> 7;
    const int d = dblk * 256 + tid;
    const int k0 = z * 128;
    float* h = smem;
    if (tid < 128) h[tid] = hidden[b * 1024 + k0 + tid];
    __syncthreads();
    float acc = (z == 0) ? b2[d] : 0.f;
#pragma unroll 8
    for (int k = 0; k < 128; ++k)
      acc += h[k] * W2[(size_t)(k0 + k) * 1024 + d];
    h2p[z * 32768 + b * 1024 + d] = acc;
  }
}

// ======== PRIMARY: 256^2-tile 8-phase bf16 GEMM, BK=64, 512 thr / 8 waves ========
// LDS per operand per dbuf: 2 k-halves x [256][32] bf16 (16KB halves, DMA-linear).
// Swizzle: LDS chunk c holds global chunk c ^ ((row>>1)&3)  (2-way = free).
// Half order per tile: H0=Bk0, H1=Ak0, H2=Bk1, H3=Ak1.
// Fragment reads are inline-asm ds_read_b128 with integer LDS addresses so the
// compiler's waitcnt pass cannot see/drain the LDS-DMA pipeline; ordering is
// entirely explicit: per-phase {s_barrier; lgkmcnt(0); sched_barrier; MFMA;
// sched_barrier; s_barrier}, plus one counted vmcnt(6) per K-tile (vmcnt(0)
// only in the tail). NO "memory" clobbers inside the loop.

#define STAGE_A(TILE, KH, BUF) {                                               \
    const int ko_ = (TILE) * 64 + (KH) * 32;                                   \
    gl_lds16(featb + a_off[0] + ko_, (char*)&ldsA[BUF][KH][0][0] + l_off0);    \
    gl_lds16(featb + a_off[1] + ko_, (char*)&ldsA[BUF][KH][0][0] + l_off1); }
#define STAGE_B(TILE, KH, BUF) {                                               \
    const int ko_ = (TILE) * 64 + (KH) * 32;                                   \
    gl_lds16(w1t + b_off[0] + ko_, (char*)&ldsB[BUF][KH][0][0] + l_off0);      \
    gl_lds16(w1t + b_off[1] + ko_, (char*)&ldsB[BUF][KH][0][0] + l_off1); }

// BUF/S/I are compile-time literals -> fold into the 16-bit ds offset field.
#define DSR_A(DST, BUF, S, I)                                                  \
  asm volatile("ds_read_b128 %0, %1 offset:%c2"                               \
               : "=v"(DST)                                                     \
               : "v"(a_rd), "i"((BUF) * 32768 + (S) * 16384 + (I) * 1024))
#define DSR_B(DST, BUF, S, J)                                                  \
  asm volatile("ds_read_b128 %0, %1 offset:%c2"                               \
               : "=v"(DST)                                                     \
               : "v"(b_rd), "i"((BUF) * 32768 + (S) * 16384 + (J) * 1024))

#define MFMA4(IB, AF)                                                          \
  acc[IB][0] = __builtin_amdgcn_mfma_f32_16x16x32_bf16(AF, bf0, acc[IB][0], 0, 0, 0); \
  acc[IB][1] = __builtin_amdgcn_mfma_f32_16x16x32_bf16(AF, bf1, acc[IB][1], 0, 0, 0); \
  acc[IB][2] = __builtin_amdgcn_mfma_f32_16x16x32_bf16(AF, bf2, acc[IB][2], 0, 0, 0); \
  acc[IB][3] = __builtin_amdgcn_mfma_f32_16x16x32_bf16(AF, bf3, acc[IB][3], 0, 0, 0);

#define WAIT_LGKM()                                                            \
  __builtin_amdgcn_s_barrier();                                                \
  asm volatile("s_waitcnt lgkmcnt(0)");                                        \
  __builtin_amdgcn_sched_barrier(0);

#define PHASE_MFMA(I0)                                                         \
  __builtin_amdgcn_s_setprio(1);                                               \
  MFMA4((I0) + 0, af0); MFMA4((I0) + 1, af1);                                  \
  MFMA4((I0) + 2, af2); MFMA4((I0) + 3, af3);                                  \
  __builtin_amdgcn_s_setprio(0);                                               \
  __builtin_amdgcn_sched_barrier(0);                                           \
  __builtin_amdgcn_s_barrier();

#define TILE_BODY(T, CUR, NXT) {                                               \
  bf16x8 af0, af1, af2, af3, bf0, bf1, bf2, bf3;                               \
  /* phase 1: kslice0, A-rows 0-3; stage (T+1).H3 = A k1 -> NXT */             \
  DSR_B(bf0, CUR, 0, 0); DSR_B(bf1, CUR, 0, 1);                                \
  DSR_B(bf2, CUR, 0, 2); DSR_B(bf3, CUR, 0, 3);                                \
  DSR_A(af0, CUR, 0, 0); DSR_A(af1, CUR, 0, 1);                                \
  DSR_A(af2, CUR, 0, 2); DSR_A(af3, CUR, 0, 3);                                \
  if ((T) + 1 < NT) STAGE_A((T) + 1, 1, NXT);                                  \
  WAIT_LGKM(); PHASE_MFMA(0);                                                  \
  /* phase 2: kslice0, A-rows 4-7; stage (T+2).H0 = B k0 -> CUR */             \
  DSR_A(af0, CUR, 0, 4); DSR_A(af1, CUR, 0, 5);                                \
  DSR_A(af2, CUR, 0, 6); DSR_A(af3, CUR, 0, 7);                                \
  if ((T) + 2 < NT) STAGE_B((T) + 2, 0, CUR);                                  \
  WAIT_LGKM(); PHASE_MFMA(4);                                                  \
  /* phase 3: kslice1, A-rows 0-3; stage (T+2).H1 = A k0 -> CUR */             \
  DSR_B(bf0, CUR, 1, 0); DSR_B(bf1, CUR, 1, 1);                                \
  DSR_B(bf2, CUR, 1, 2); DSR_B(bf3, CUR, 1, 3);                                \
  DSR_A(af0, CUR, 1, 0); DSR_A(af1, CUR, 1, 1);                                \
  DSR_A(af2, CUR, 1, 2); DSR_A(af3, CUR, 1, 3);                                \
  if ((T) + 2 < NT) STAGE_A((T) + 2, 0, CUR);                                  \
  WAIT_LGKM(); PHASE_MFMA(0);                                                  \
  /* phase 4: kslice1, A-rows 4-7; stage (T+2).H2 = B k1 -> CUR; tile wait */  \
  DSR_A(af0, CUR, 1, 4); DSR_A(af1, CUR, 1, 5);                                \
  DSR_A(af2, CUR, 1, 6); DSR_A(af3, CUR, 1, 7);                                \
  if ((T) + 2 < NT) STAGE_B((T) + 2, 1, CUR);                                  \
  if ((T) < NT - 2) { asm volatile("s_waitcnt vmcnt(6)"); }                    \
  else              { asm volatile("s_waitcnt vmcnt(0)"); }                    \
  WAIT_LGKM(); PHASE_MFMA(4);                                                  \
}

__global__ __launch_bounds__(512, 2) void gemm_score_8ph_kernel(
    const ushort* __restrict__ featb,  // bf16 [32768][1024]
    const ushort* __restrict__ w1t,    // bf16 [1024][1024]
    const float* __restrict__ b1, const float* __restrict__ h2p,
    const float* __restrict__ wp, float* __restrict__ score_p) {
  __shared__ ushort ldsA[2][2][256][32];  // [buf][khalf][row][k] 64KB
  __shared__ ushort ldsB[2][2][256][32];  // 64KB
  __shared__ float hbl[256], wpl[256];
  __shared__ float sred[2][3][128];

  const int tid = threadIdx.x;
  const int row0 = blockIdx.x * 256;
  const int col0 = blockIdx.y * 256;
  const int b = row0 >> 10;
  const int wave = tid >> 6, lane = tid & 63;
  const int wm = wave >> 2, wn = wave & 3;  // 2M x 4N
  const int lrow = lane & 15, quad = lane >> 4;

  // preloop: hb (b1 + sum of h2 partials) and wp slices for this col block
  if (tid < 256) {
    const int d = col0 + tid;
    float hv = b1[d];
#pragma unroll
    for (int p = 0; p < 8; ++p) hv += h2p[p * 32768 + b * 1024 + d];
    hbl[tid] = hv;
  } else {
    wpl[tid - 256] = wp[col0 + tid - 256];
  }

  // staging offsets: slot s covers (row r=s>>2, lds-chunk c=s&3) of a 16KB half;
  // source global chunk q = c ^ ((r>>1)&3)  (pre-swizzled source, linear dest)
  int a_off[2], b_off[2];
  int l_off0, l_off1;
  {
    const int s0 = wave * 128 + lane;
    const int r0 = s0 >> 2, c0 = s0 & 3;
    const int q0 = c0 ^ ((r0 >> 1) & 3);
    a_off[0] = (row0 + r0) * 1024 + q0 * 8;
    b_off[0] = (col0 + r0) * 1024 + q0 * 8;
    const int s1 = s0 + 64;
    const int r1 = s1 >> 2, c1 = s1 & 3;
    const int q1 = c1 ^ ((r1 >> 1) & 3);
    a_off[1] = (row0 + r1) * 1024 + q1 * 8;
    b_off[1] = (col0 + r1) * 1024 + q1 * 8;
    l_off0 = (wave * 128) * 16;       // wave-uniform LDS byte base, lane*16 by HW
    l_off1 = (wave * 128 + 64) * 16;
  }

  // read-side LDS byte addresses (runtime part only; (BUF,S,I) in offset imm).
  // chunkXor = quad ^ ((r>>1)&3) collapses to quad ^ ((lrow>>1)&3): the i*16 and
  // wm*128 / wn*64 row components are all ≡0 mod 8 so they don't affect bits 1-2.
  const unsigned chunk16 = (unsigned)((quad ^ ((lrow >> 1) & 3)) * 16);
  const unsigned a_rd = lds32(&ldsA[0][0][0][0]) + (wm * 128 + lrow) * 64 + chunk16;
  const unsigned b_rd = lds32(&ldsB[0][0][0][0]) + (wn * 64 + lrow) * 64 + chunk16;

  f32x4 acc[8][4] = {};

  // prologue: tile0 fully (H0..H3) + tile1 H0..H2 = 14 loads; wait 8 oldest.
  STAGE_B(0, 0, 0); STAGE_A(0, 0, 0); STAGE_B(0, 1, 0); STAGE_A(0, 1, 0);
  STAGE_B(1, 0, 1); STAGE_A(1, 0, 1); STAGE_B(1, 1, 1);
  asm volatile("s_waitcnt vmcnt(6)");
  __builtin_amdgcn_s_barrier();

  for (int t = 0; t < NT; t += 2) {
    TILE_BODY(t, 0, 1);
    TILE_BODY(t + 1, 1, 0);
  }

  // ---- epilogue: score partial per row over this 256-col block ----
  float hbv[4], wpv[4];
#pragma unroll
  for (int j = 0; j < 4; ++j) {
    const int idx = wn * 64 + j * 16 + lrow;
    hbv[j] = hbl[idx];
    wpv[j] = wpl[idx];
  }
  float rs[8][4];
#pragma unroll
  for (int i = 0; i < 8; ++i) {
#pragma unroll
    for (int r = 0; r < 4; ++r) {
      float s = 0.f;
#pragma unroll
      for (int j = 0; j < 4; ++j)
        s += tanh_fast(acc[i][j][r] + hbv[j]) * wpv[j];
      s += __shfl_xor(s, 8);
      s += __shfl_xor(s, 4);
      s += __shfl_xor(s, 2);
      s += __shfl_xor(s, 1);
      rs[i][r] = s;
    }
  }
  if (wn != 0 && lrow == 0) {
#pragma unroll
    for (int i = 0; i < 8; ++i)
#pragma unroll
      for (int r = 0; r < 4; ++r)
        sred[wm][wn - 1][i * 16 + quad * 4 + r] = rs[i][r];
  }
  __syncthreads();
  if (wn == 0 && lrow == 0) {
#pragma unroll
    for (int i = 0; i < 8; ++i)
#pragma unroll
      for (int r = 0; r < 4; ++r) {
        const int ro = i * 16 + quad * 4 + r;
        score_p[(size_t)blockIdx.y * 32768 + row0 + wm * 128 + ro] =
            rs[i][r] + sred[wm][0][ro] + sred[wm][1][ro] + sred[wm][2][ro];
      }
  }
  // keep-alive: give the LDS-DMA'd buffers a visible reader (never taken;
  // hbl comes from memory so the compiler can't fold the condition).
  if (tid == 0 && hbl[0] == 1234567.0f)
    score_p[0] = (float)ldsA[0][0][0][0] + (float)ldsB[0][0][0][0];
}

// ======== FALLBACK (small ws): staging-cvt GEMM, fp32 feat direct ========
#define GEMM_PRELOOP()                                                         \
  if (tid < 128) {                                                             \
    const int d = col0 + tid;                                                  \
    float hv = b1[d];                                                          \
    _Pragma("unroll") for (int p = 0; p < 8; ++p)                              \
        hv += h2p[p * 32768 + b * 1024 + d];                                   \
    hbl[tid] = hv;                                                             \
  } else {                                                                     \
    wpl[tid - 128] = wp[col0 + tid - 128];                                     \
  }

#define GEMM_EPILOGUE(ROWG)                                                    \
  float hbv[4], wpv[4];                                                        \
  _Pragma("unroll") for (int j = 0; j < 4; ++j) {                              \
    const int idx = wn * 64 + j * 16 + lrow;                                   \
    hbv[j] = hbl[idx];                                                         \
    wpv[j] = wpl[idx];                                                         \
  }                                                                            \
  float rsum[4][4];                                                            \
  _Pragma("unroll") for (int i = 0; i < 4; ++i) {                              \
    _Pragma("unroll") for (int r = 0; r < 4; ++r) {                            \
      float s = 0.f;                                                           \
      _Pragma("unroll") for (int j = 0; j < 4; ++j)                            \
          s += tanh_fast(acc[i][j][r] + hbv[j]) * wpv[j];                      \
      s += __shfl_xor(s, 8);                                                   \
      s += __shfl_xor(s, 4);                                                   \
      s += __shfl_xor(s, 2);                                                   \
      s += __shfl_xor(s, 1);                                                   \
      rsum[i][r] = s;                                                          \
    }                                                                          \
  }                                                                            \
  if (wn == 1 && lrow == 0) {                                                  \
    _Pragma("unroll") for (int i = 0; i < 4; ++i)                              \
        _Pragma("unroll") for (int r = 0; r < 4; ++r)                          \
            sred[wm][i * 16 + quad * 4 + r] = rsum[i][r];                      \
  }                                                                            \
  __syncthreads();                                                             \
  if (wn == 0 && lrow == 0) {                                                  \
    _Pragma("unroll") for (int i = 0; i < 4; ++i)                              \
        _Pragma("unroll") for (int r = 0; r < 4; ++r) {                        \
          const int ro = wm * 64 + i * 16 + quad * 4 + r;                      \
          score_p[(size_t)blockIdx.y * 32768 + (ROWG) + ro] =                  \
              rsum[i][r] + sred[wm][ro & 63];                                  \
        }                                                                      \
  }

__global__ __launch_bounds__(256) void gemm_score_cvt_kernel(
    const float* __restrict__ feat, const ushort* __restrict__ w1t,
    const float* __restrict__ b1, const float* __restrict__ h2p,
    const float* __restrict__ wp, float* __restrict__ score_p) {
  __shared__ ushort ldsA[BM * LDK];
  __shared__ ushort ldsB[BN * LDK];
  __shared__ float sred[2][64];
  __shared__ float hbl[128], wpl[128];
  const int tid = threadIdx.x;
  const int row0 = blockIdx.x * BM;
  const int col0 = blockIdx.y * BN;
  const int b = row0 >> 10;

  const int wave = tid >> 6, lane = tid & 63;
  const int wm = wave & 1, wn = wave >> 1;
  const int lrow = lane & 15, quad = lane >> 4;

  GEMM_PRELOOP()

  const int arow = tid >> 1;
  const int akof = (tid & 1) * 16;
  const int brow = tid >> 2;
  const int bkof = (tid & 3) * 8;

  f32x4 acc[4][4] = {};

  for (int k0 = 0; k0 < 1024; k0 += 32) {
    {
      const float* ap = feat + (size_t)(row0 + arow) * 1024 + k0 + akof;
      float4 v0 = *(const float4*)(ap + 0);
      float4 v1 = *(const float4*)(ap + 4);
      float4 v2 = *(const float4*)(ap + 8);
      float4 v3 = *(const float4*)(ap + 12);
      union { bf16x8 v; int4 i; } w0, w1;
      w0.v = cvt8(v0, v1);
      w1.v = cvt8(v2, v3);
      *(int4*)&ldsA[arow * LDK + akof] = w0.i;
      *(int4*)&ldsA[arow * LDK + akof + 8] = w1.i;
    }
#pragma unroll
    for (int p = 0; p < 2; ++p) {
      const int m = p * 64 + brow;
      *(int4*)&ldsB[m * LDK + bkof] =
          *(const int4*)(w1t + (size_t)(col0 + m) * 1024 + k0 + bkof);
    }
    __syncthreads();
    bf16x8 af[4], bfr[4];
#pragma unroll
    for (int i = 0; i < 4; ++i)
      af[i] = *(const bf16x8*)&ldsA[(wm * 64 + i * 16 + lrow) * LDK + quad * 8];
#pragma unroll
    for (int j = 0; j < 4; ++j)
      bfr[j] = *(const bf16x8*)&ldsB[(wn * 64 + j * 16 + lrow) * LDK + quad * 8];
#pragma unroll
    for (int i = 0; i < 4; ++i)
#pragma unroll
      for (int j = 0; j < 4; ++j)
        acc[i][j] = __builtin_amdgcn_mfma_f32_16x16x32_bf16(
            af[i], bfr[j], acc[i][j], 0, 0, 0);
    __syncthreads();
  }

  GEMM_EPILOGUE(row0)
}

// -------- softmax over L per b (sums np partials); also zeroes out[b][:] --------
__global__ __launch_bounds__(256) void softmax_kernel(
    const float* __restrict__ score_p, float* __restrict__ w,
    float* __restrict__ out, int np) {
  const int b = blockIdx.x, tid = threadIdx.x;
  const int lane = tid & 63, wv = tid >> 6;
  __shared__ float sm[4], ss[4];
  float v[4];
  float mx = -1e30f;
#pragma unroll
  for (int i = 0; i < 4; ++i) {
    const int idx = b * 1024 + i * 256 + tid;
    out[idx] = 0.f;  // d_out poisoned; context atomicAdds later
    float s = 0.f;
    for (int p = 0; p < np; ++p) s += score_p[p * 32768 + idx];
    v[i] = s;
    mx = fmaxf(mx, s);
  }
#pragma unroll
  for (int off = 32; off; off >>= 1) mx = fmaxf(mx, __shfl_xor(mx, off));
  if (lane == 0) sm[wv] = mx;
  __syncthreads();
  mx = fmaxf(fmaxf(sm[0], sm[1]), fmaxf(sm[2], sm[3]));
  float sum = 0.f;
#pragma unroll
  for (int i = 0; i < 4; ++i) {
    v[i] = __expf(v[i] - mx);
    sum += v[i];
  }
#pragma unroll
  for (int off = 32; off; off >>= 1) sum += __shfl_xor(sum, off);
  if (lane == 0) ss[wv] = sum;
  __syncthreads();
  const float inv = 1.f / (ss[0] + ss[1] + ss[2] + ss[3]);
#pragma unroll
  for (int i = 0; i < 4; ++i) w[b * 1024 + i * 256 + tid] = v[i] * inv;
}

// -------- out[b][f] += sum_{l in 64-chunk} w[b][l]*feat[b][l][f] (fp32) --------
__global__ __launch_bounds__(256) void context_kernel(
    const float* __restrict__ w, const float* __restrict__ feat,
    float* __restrict__ out) {
  const int b = blockIdx.y;
  const int l0 = blockIdx.x * 64;
  const int f0 = threadIdx.x * 4;
  __shared__ float wl[64];
  if (threadIdx.x < 64) wl[threadIdx.x] = w[b * 1024 + l0 + threadIdx.x];
  __syncthreads();
  const float* fb = feat + (size_t)b * 1048576 + (size_t)l0 * 1024 + f0;
  float a0 = 0.f, a1 = 0.f, a2 = 0.f, a3 = 0.f;
#pragma unroll 8
  for (int l = 0; l < 64; ++l) {
    float4 v = *(const float4*)(fb + (size_t)l * 1024);
    const float wv = wl[l];
    a0 += wv * v.x;
    a1 += wv * v.y;
    a2 += wv * v.z;
    a3 += wv * v.w;
  }
  float* dst = out + b * 1024 + f0;
  atomicAdd(dst + 0, a0);
  atomicAdd(dst + 1, a1);
  atomicAdd(dst + 2, a2);
  atomicAdd(dst + 3, a3);
}

extern "C" void kernel_launch(void* const* d_in, const int* in_sizes, int n_in,
                              void* d_out, int out_size, void* d_ws, size_t ws_size,
                              hipStream_t stream) {
  const float* feat   = (const float*)d_in[0];
  const float* hidden = (const float*)d_in[1];
  const float* W1     = (const float*)d_in[2];
  const float* b1     = (const float*)d_in[3];
  const float* W2     = (const float*)d_in[4];
  const float* b2     = (const float*)d_in[5];
  const float* Wp     = (const float*)d_in[6];
  float* out = (float*)d_out;

  char* ws = (char*)d_ws;
  ushort* w1t    = (ushort*)ws;                  // 2 MB
  float* score_p = (float*)(ws + 2097152);       // 1 MB region ([4] or [8] x 32768)
  float* h2p     = (float*)(ws + 3145728);       // 1 MB [8][32768]
  float* wts     = (float*)(ws + 4194304);       // 128 KB
  ushort* featb  = (ushort*)(ws + 4325376);      // 64 MB (primary path only)
  const bool big_ws = ws_size >= (size_t)(4325376 + 67108864);

  if (big_ws) {
    // full-batch prep: cvt 16384 blocks + transpose 256 + h2 1024
    prep_kernel<<<17664, 256, 0, stream>>>(feat, featb, W1, w1t, hidden, W2, b2,
                                           h2p, 16384);
    gemm_score_8ph_kernel<<<dim3(128, 4), 512, 0, stream>>>(featb, w1t, b1, h2p,
                                                            Wp, score_p);
    softmax_kernel<<<32, 256, 0, stream>>>(score_p, wts, out, 4);
  } else {
    prep_kernel<<<1280, 256, 0, stream>>>(feat, featb, W1, w1t, hidden, W2, b2,
                                          h2p, 0);
    gemm_score_cvt_kernel<<<dim3(256, 8), 256, 0, stream>>>(feat, w1t, b1, h2p,
                                                            Wp, score_p);
    softmax_kernel<<<32, 256, 0, stream>>>(score_p, wts, out, 8);
  }

  context_kernel<<<dim3(16, 32), 256, 0, stream>>>(wts, feat, out);
}